// Round 5
// baseline (138.591 us; speedup 1.0000x reference)
//
#include <hip/hip_runtime.h>
#include <hip/hip_bf16.h>

#define B_  512
#define T_  256
#define C_  384
#define H_  64
#define SCALE_ 0.05103103630798287f   // 384^-0.5

typedef float f32x4  __attribute__((ext_vector_type(4)));
typedef short bf16x8 __attribute__((ext_vector_type(8)));
typedef short bf16x4 __attribute__((ext_vector_type(4)));

__device__ __forceinline__ unsigned short f2bf(float f) {
    union { float f; unsigned u; } v; v.f = f;
    unsigned r = v.u + 0x7FFFu + ((v.u >> 16) & 1u);   // RNE
    return (unsigned short)(r >> 16);
}

__device__ __forceinline__ unsigned cvt_pk_bf16(float lo, float hi) {
    unsigned r;
    asm("v_cvt_pk_bf16_f32 %0, %1, %2" : "=v"(r) : "v"(lo), "v"(hi));
    return r;
}

// XOR-swizzled [R][64]-short tile index (row = 128 B = 8 x 16B blocks).
__device__ __forceinline__ int swz64(int row, int col) {
    return row * 64 + (((col >> 3) ^ (row & 7)) << 3) + (col & 7);
}

// LDS layout (shorts), total 74752 shorts = 149504 B:
//  [0,     7680)   wst0 [192][40]  (k=32 chunk, rows padded 32->40 shorts = conflict-free b128)
//  [7680,  15360)  wst1 (double buffer)
//  [15360, 25600)  Pb: 16 waves x [16][40]
//  [25600, 41984)  Ks[256][64] swz64
//  [41984, 58368)  Qs[256][64] swz64
//  [58368, 74752)  Vt[64][256] swz (h-major)
//
// Phase-1 wave grid: 8 row-bands (32 rows = 2 strips) x 2 col-halves (96 cols).
// Each W^T b128 fragment feeds 2 MFMAs; per-CU B-read bytes halved vs 1-D grid.
__global__ __launch_bounds__(1024, 4) void att_head_kernel(
    const float* __restrict__ x,  const float* __restrict__ Wk,
    const float* __restrict__ Wq, const float* __restrict__ Wv,
    float* __restrict__ out)
{
    __shared__ __align__(16) short smem[74752];
    short* const wst0 = smem;
    short* const wst1 = smem + 7680;
    short* const Pb   = smem + 15360;
    short* const Ks   = smem + 25600;
    short* const Qs   = smem + 41984;
    short* const Vt   = smem + 58368;

    const int tid  = threadIdx.x;
    const int b    = blockIdx.x;
    const int w    = tid >> 6;        // 0..15
    const int lane = tid & 63;
    const int g    = lane >> 4;
    const int i    = lane & 15;
    const int wr   = w >> 1;          // row band (32 rows)
    const int wc   = w & 1;           // col half (96 cols)

    const float* xb = x + (size_t)b * T_ * C_;

    // x per-lane bases (strip0 rows 32wr+i, strip1 +16); chunk offset is 32j floats (imm-friendly)
    const float* xs0 = xb + (size_t)(32 * wr + i) * C_ + g * 8;
    const float* xs1 = xs0 + 16 * C_;

    // W staging: thread -> (n, kp) with n=tid>>4 (0..63), kp=tid&15; loads m=Wk/Wq/Wv, d=0/1
    const int nW  = tid >> 4;
    const int kpW = tid & 15;

    f32x4 accP[2][6];
    #pragma unroll
    for (int m = 0; m < 2; m++)
        #pragma unroll
        for (int nb = 0; nb < 6; nb++) accP[m][nb] = f32x4{0.f, 0.f, 0.f, 0.f};

    float  wfa[6];
    float4 nxr[4];
    bf16x8 afs[2];

    auto issueW = [&](int j) {
        const int base = j * 2048 + kpW * 128 + nW;   // elem idx (k*64+n), k=32j+2kp(+d)
        wfa[0] = Wk[base]; wfa[1] = Wk[base + 64];
        wfa[2] = Wq[base]; wfa[3] = Wq[base + 64];
        wfa[4] = Wv[base]; wfa[5] = Wv[base + 64];
    };
    auto issueX = [&](int j) {
        nxr[0] = *(const float4*)(xs0 + 32 * j);
        nxr[1] = *(const float4*)(xs0 + 32 * j + 4);
        nxr[2] = *(const float4*)(xs1 + 32 * j);
        nxr[3] = *(const float4*)(xs1 + 32 * j + 4);
    };
    auto writeW = [&](short* buf) {
        #pragma unroll
        for (int m = 0; m < 3; m++) {
            const unsigned u = cvt_pk_bf16(wfa[2 * m], wfa[2 * m + 1]);
            *(unsigned*)&buf[(m * 64 + nW) * 40 + kpW * 2] = u;
        }
    };
    auto cvtX = [&]() {
        #pragma unroll
        for (int s = 0; s < 2; s++) {
            union { bf16x8 v; unsigned u[4]; } a;
            a.u[0] = cvt_pk_bf16(nxr[2 * s].x, nxr[2 * s].y);
            a.u[1] = cvt_pk_bf16(nxr[2 * s].z, nxr[2 * s].w);
            a.u[2] = cvt_pk_bf16(nxr[2 * s + 1].x, nxr[2 * s + 1].y);
            a.u[3] = cvt_pk_bf16(nxr[2 * s + 1].z, nxr[2 * s + 1].w);
            afs[s] = a.v;
        }
    };

    // ---------------- Phase 1: QKV projection, 12 chunks of k=32 ----------------
    issueW(0); issueX(0);
    writeW(wst0);
    cvtX();
    asm volatile("s_waitcnt lgkmcnt(0)\n\ts_barrier" ::: "memory");

    #pragma unroll
    for (int j = 0; j < 12; j++) {
        if (j < 11) { issueW(j + 1); issueX(j + 1); }   // in flight across the block
        short* const cur = (j & 1) ? wst1 : wst0;
        __builtin_amdgcn_s_setprio(1);
        #pragma unroll
        for (int nb = 0; nb < 6; nb++) {
            const int row = 96 * wc + 16 * nb + i;
            const bf16x8 bfr = *(const bf16x8*)&cur[row * 40 + g * 8];
            accP[0][nb] = __builtin_amdgcn_mfma_f32_16x16x32_bf16(afs[0], bfr, accP[0][nb], 0, 0, 0);
            accP[1][nb] = __builtin_amdgcn_mfma_f32_16x16x32_bf16(afs[1], bfr, accP[1][nb], 0, 0, 0);
        }
        __builtin_amdgcn_s_setprio(0);
        if (j < 11) { writeW((j & 1) ? wst0 : wst1); cvtX(); }   // T14: write late, loads aged
        asm volatile("s_waitcnt lgkmcnt(0)\n\ts_barrier" ::: "memory");
    }

    // ---------------- Epilogue: scatter K,Q (b16) and V (packed b64) ----------------
    #pragma unroll
    for (int m = 0; m < 2; m++) {
        const int row0 = 32 * wr + 16 * m + 4 * g;
        #pragma unroll
        for (int nb = 0; nb < 6; nb++) {
            const int gc = 96 * wc + 16 * nb;   // wave-uniform
            if (gc < 64) {
                #pragma unroll
                for (int r = 0; r < 4; r++)
                    Ks[swz64(row0 + r, gc + i)] = (short)f2bf(accP[m][nb][r]);
            } else if (gc < 128) {
                #pragma unroll
                for (int r = 0; r < 4; r++)
                    Qs[swz64(row0 + r, gc - 64 + i)] = (short)f2bf(accP[m][nb][r]);
            } else {
                const int hrow = gc - 128 + i;
                const int t0   = row0;
                bf16x4 pk;
                #pragma unroll
                for (int r = 0; r < 4; r++) pk[r] = (short)f2bf(accP[m][nb][r]);
                const int blk = t0 >> 3;
                *(bf16x4*)&Vt[hrow * 256 + (((blk & ~7) | ((blk ^ (hrow & 7)) & 7)) << 3) + (t0 & 7)] = pk;
            }
        }
    }
    asm volatile("s_waitcnt lgkmcnt(0)\n\ts_barrier" ::: "memory");

    // ---------------- Phase 2: causal attention (wave w owns rows [16w,16w+16)) ------
    const int rb = 16 * w;
    bf16x8 qf[2];
    #pragma unroll
    for (int ks = 0; ks < 2; ks++)
        qf[ks] = *(const bf16x8*)&Qs[(rb + i) * 64 + (((ks * 4 + g) ^ (i & 7)) << 3)];

    short* myP = Pb + w * 640;                 // [16][40] shorts, block-swizzled
    const float NEG_INF = -__builtin_inff();
    const int lim = w;

    f32x4 accS[16];
    #pragma unroll
    for (int nt = 0; nt < 16; nt++) accS[nt] = f32x4{0.f, 0.f, 0.f, 0.f};

    #pragma unroll
    for (int nt = 0; nt < 16; nt++) {
        if (nt <= lim) {
            #pragma unroll
            for (int ks = 0; ks < 2; ks++) {
                const bf16x8 kf = *(const bf16x8*)&Ks[(nt * 16 + i) * 64 + (((ks * 4 + g) ^ (i & 7)) << 3)];
                accS[nt] = __builtin_amdgcn_mfma_f32_16x16x32_bf16(qf[ks], kf, accS[nt], 0, 0, 0);
            }
        }
    }

    float mrow[4] = { NEG_INF, NEG_INF, NEG_INF, NEG_INF };
    #pragma unroll
    for (int nt = 0; nt < 16; nt++)
        #pragma unroll
        for (int r = 0; r < 4; r++) {
            const int col = nt * 16 + i;
            const int row = rb + 4 * g + r;
            float v = accS[nt][r] * SCALE_;
            v = (col <= row) ? v : NEG_INF;
            accS[nt][r] = v;
            mrow[r] = fmaxf(mrow[r], v);
        }
    #pragma unroll
    for (int r = 0; r < 4; r++)
        #pragma unroll
        for (int msk = 1; msk < 16; msk <<= 1)
            mrow[r] = fmaxf(mrow[r], __shfl_xor(mrow[r], msk, 64));

    float lsum[4] = { 0.f, 0.f, 0.f, 0.f };
    #pragma unroll
    for (int nt = 0; nt < 16; nt++)
        #pragma unroll
        for (int r = 0; r < 4; r++) {
            const float p = __expf(accS[nt][r] - mrow[r]);
            accS[nt][r] = p;
            lsum[r] += p;
        }
    #pragma unroll
    for (int r = 0; r < 4; r++)
        #pragma unroll
        for (int msk = 1; msk < 16; msk <<= 1)
            lsum[r] += __shfl_xor(lsum[r], msk, 64);

    f32x4 accO[4];
    #pragma unroll
    for (int ht = 0; ht < 4; ht++) accO[ht] = f32x4{0.f, 0.f, 0.f, 0.f};

    #pragma unroll
    for (int ck = 0; ck < 8; ck++) {
        if (2 * ck <= lim) {
            #pragma unroll
            for (int t2 = 0; t2 < 2; t2++)
                #pragma unroll
                for (int r = 0; r < 4; r++) {
                    const int q = 4 * g + r, kk = t2 * 16 + i;
                    myP[q * 40 + ((((kk >> 3) ^ (q >> 2)) & 3) << 3) + (kk & 7)] =
                        (short)f2bf(accS[2 * ck + t2][r]);
                }
            asm volatile("s_waitcnt lgkmcnt(0)" ::: "memory");
            const bf16x8 pf = *(const bf16x8*)&myP[i * 40 + (((g ^ (i >> 2)) & 3) << 3)];
            #pragma unroll
            for (int ht = 0; ht < 4; ht++) {
                const int hrow = ht * 16 + i;
                const int blk  = ck * 4 + g;
                const bf16x8 vf = *(const bf16x8*)&Vt[hrow * 256 +
                        (((blk & ~7) | ((blk ^ (hrow & 7)) & 7)) << 3)];
                accO[ht] = __builtin_amdgcn_mfma_f32_16x16x32_bf16(pf, vf, accO[ht], 0, 0, 0);
            }
        }
    }

    float inv[4];
    #pragma unroll
    for (int r = 0; r < 4; r++) inv[r] = 1.f / lsum[r];
    #pragma unroll
    for (int ht = 0; ht < 4; ht++)
        #pragma unroll
        for (int r = 0; r < 4; r++) {
            const int row = rb + 4 * g + r;
            out[((size_t)b * T_ + row) * H_ + ht * 16 + i] = accO[ht][r] * inv[r];
        }
}

extern "C" void kernel_launch(void* const* d_in, const int* in_sizes, int n_in,
                              void* d_out, int out_size, void* d_ws, size_t ws_size,
                              hipStream_t stream) {
    const float* x  = (const float*)d_in[0];
    const float* Wk = (const float*)d_in[1];
    const float* Wq = (const float*)d_in[2];
    const float* Wv = (const float*)d_in[3];
    float* out = (float*)d_out;
    (void)d_ws; (void)ws_size; (void)in_sizes; (void)n_in; (void)out_size;
    att_head_kernel<<<dim3(B_), dim3(1024), 0, stream>>>(x, Wk, Wq, Wv, out);
}

// Round 7
// 73.585 us; speedup vs baseline: 1.8834x; 1.8834x over previous
//
#include <hip/hip_runtime.h>
#include <hip/hip_bf16.h>

#define B_  512
#define T_  256
#define C_  384
#define H_  64
#define SCALE_ 0.05103103630798287f   // 384^-0.5

typedef float f32x4  __attribute__((ext_vector_type(4)));
typedef short bf16x8 __attribute__((ext_vector_type(8)));
typedef short bf16x4 __attribute__((ext_vector_type(4)));

__device__ __forceinline__ unsigned short f2bf(float f) {
    union { float f; unsigned u; } v; v.f = f;
    unsigned r = v.u + 0x7FFFu + ((v.u >> 16) & 1u);   // RNE
    return (unsigned short)(r >> 16);
}

__device__ __forceinline__ unsigned cvt_pk_bf16(float lo, float hi) {
    unsigned r;
    asm("v_cvt_pk_bf16_f32 %0, %1, %2" : "=v"(r) : "v"(lo), "v"(hi));
    return r;
}

// LDS (shorts), total 75264 shorts = 150528 B. All strides padded +16B -> every
// wave-wide b128 read is bank-BALANCED (optimal 8-phase), no swizzles needed.
//  Phase-1 view:  Wl[192][392]   (full W^T resident, bf16)
//  Phase-2 view (aliased, written after all Wl reads done):
//    [0,     10240)  Pb: 16 waves x [16][40]
//    [10240, 28672)  Ks[256][72]
//    [28672, 47104)  Qs[256][72]
//    [47104, 64000)  Vt[64][264]  (h-major, t contiguous)
//
// Phase 1 is barrier-free: wave grid 8 row-bands (32 rows = 2 strips) x 2 col-halves
// (96 cols = 6 frags). 3 barriers total in the kernel.
__global__ __launch_bounds__(1024, 4) void att_head_kernel(
    const float* __restrict__ x,  const float* __restrict__ Wk,
    const float* __restrict__ Wq, const float* __restrict__ Wv,
    float* __restrict__ out)
{
    __shared__ __align__(16) short smem[75264];

    const int tid  = threadIdx.x;
    const int b    = blockIdx.x;
    const int w    = tid >> 6;        // 0..15
    const int lane = tid & 63;
    const int g    = lane >> 4;
    const int i    = lane & 15;
    const int wr   = w >> 1;          // row band (32 rows)
    const int wc   = w & 1;           // col half (96 cols)

    const float* xb = x + (size_t)b * T_ * C_;

    // ---- Stage W^T -> LDS once: Wl[m*64+n][k] = Wm[k][n], coalesced reads ----
    {
        const int n  = tid & 63;      // lane -> contiguous n (256B/load/wave)
        const int kq = tid >> 6;      // k-quad index
        const float* Wsrc[3] = { Wk, Wq, Wv };
        #pragma unroll
        for (int m = 0; m < 3; m++) {
            const float* Wp = Wsrc[m] + n;
            short* dst = smem + (m * 64 + n) * 392;
            #pragma unroll
            for (int kk = 0; kk < 6; kk++) {
                const int k = 4 * kq + 64 * kk;
                union { bf16x4 v; unsigned u[2]; } p;
                p.u[0] = cvt_pk_bf16(Wp[(size_t)(k + 0) * H_], Wp[(size_t)(k + 1) * H_]);
                p.u[1] = cvt_pk_bf16(Wp[(size_t)(k + 2) * H_], Wp[(size_t)(k + 3) * H_]);
                *(bf16x4*)&dst[k] = p.v;
            }
        }
    }
    asm volatile("s_waitcnt lgkmcnt(0)\n\ts_barrier" ::: "memory");

    // ---- Phase 1: QKV projection, 6 chunks of k=64, NO barriers ----
    const float* xs0 = xb + (size_t)(32 * wr + i) * C_ + g * 8;   // strip 0 rows
    const float* xs1 = xs0 + 16 * C_;                             // strip 1 rows
    const short* wl0 = smem + (96 * wc + i) * 392 + g * 8;        // B rows 96wc+16nb+i

    f32x4 accP[2][6];
    #pragma unroll
    for (int m = 0; m < 2; m++)
        #pragma unroll
        for (int nb = 0; nb < 6; nb++) accP[m][nb] = f32x4{0.f, 0.f, 0.f, 0.f};

    #pragma unroll 2
    for (int j = 0; j < 6; j++) {
        float4 xv[2][4];
        #pragma unroll
        for (int ks = 0; ks < 2; ks++) {
            xv[0][2 * ks]     = *(const float4*)(xs0 + 64 * j + 32 * ks);
            xv[0][2 * ks + 1] = *(const float4*)(xs0 + 64 * j + 32 * ks + 4);
            xv[1][2 * ks]     = *(const float4*)(xs1 + 64 * j + 32 * ks);
            xv[1][2 * ks + 1] = *(const float4*)(xs1 + 64 * j + 32 * ks + 4);
        }
        bf16x8 afs[2][2];
        #pragma unroll
        for (int m = 0; m < 2; m++)
            #pragma unroll
            for (int ks = 0; ks < 2; ks++) {
                union { bf16x8 v; unsigned u[4]; } a;
                a.u[0] = cvt_pk_bf16(xv[m][2 * ks].x,     xv[m][2 * ks].y);
                a.u[1] = cvt_pk_bf16(xv[m][2 * ks].z,     xv[m][2 * ks].w);
                a.u[2] = cvt_pk_bf16(xv[m][2 * ks + 1].x, xv[m][2 * ks + 1].y);
                a.u[3] = cvt_pk_bf16(xv[m][2 * ks + 1].z, xv[m][2 * ks + 1].w);
                afs[m][ks] = a.v;
            }
        #pragma unroll
        for (int nb = 0; nb < 6; nb++) {
            #pragma unroll
            for (int ks = 0; ks < 2; ks++) {
                const bf16x8 bfr = *(const bf16x8*)&wl0[nb * 16 * 392 + 64 * j + 32 * ks];
                accP[0][nb] = __builtin_amdgcn_mfma_f32_16x16x32_bf16(afs[0][ks], bfr, accP[0][nb], 0, 0, 0);
                accP[1][nb] = __builtin_amdgcn_mfma_f32_16x16x32_bf16(afs[1][ks], bfr, accP[1][nb], 0, 0, 0);
            }
        }
    }
    // all waves must finish reading Wl before it is overwritten by K/Q/V
    asm volatile("s_waitcnt lgkmcnt(0)\n\ts_barrier" ::: "memory");

    short* const Pb = smem;
    short* const Ks = smem + 10240;
    short* const Qs = smem + 28672;
    short* const Vt = smem + 47104;

    // ---- Epilogue: scatter K,Q (b16) and V (packed b64) to LDS ----
    #pragma unroll
    for (int m = 0; m < 2; m++) {
        const int row0 = 32 * wr + 16 * m + 4 * g;
        #pragma unroll
        for (int nb = 0; nb < 6; nb++) {
            const int gc = 96 * wc + 16 * nb;   // wave-uniform
            if (gc < 64) {
                #pragma unroll
                for (int r = 0; r < 4; r++)
                    Ks[(row0 + r) * 72 + gc + i] = (short)f2bf(accP[m][nb][r]);
            } else if (gc < 128) {
                #pragma unroll
                for (int r = 0; r < 4; r++)
                    Qs[(row0 + r) * 72 + gc - 64 + i] = (short)f2bf(accP[m][nb][r]);
            } else {
                const int hrow = gc - 128 + i;
                bf16x4 pk;
                #pragma unroll
                for (int r = 0; r < 4; r++) pk[r] = (short)f2bf(accP[m][nb][r]);
                *(bf16x4*)&Vt[hrow * 264 + row0] = pk;
            }
        }
    }
    asm volatile("s_waitcnt lgkmcnt(0)\n\ts_barrier" ::: "memory");

    // ---- Phase 2: causal attention (wave w owns rows [16w,16w+16)) ----
    const int rb = 16 * w;
    bf16x8 qf[2];
    #pragma unroll
    for (int ks = 0; ks < 2; ks++)
        qf[ks] = *(const bf16x8*)&Qs[(rb + i) * 72 + ks * 32 + g * 8];

    short* myP = Pb + w * 640;                 // [16][40] shorts
    const float NEG_INF = -__builtin_inff();
    const int lim = w;

    f32x4 accS[16];
    #pragma unroll
    for (int nt = 0; nt < 16; nt++) accS[nt] = f32x4{0.f, 0.f, 0.f, 0.f};

    #pragma unroll
    for (int nt = 0; nt < 16; nt++) {
        if (nt <= lim) {
            #pragma unroll
            for (int ks = 0; ks < 2; ks++) {
                const bf16x8 kf = *(const bf16x8*)&Ks[(nt * 16 + i) * 72 + ks * 32 + g * 8];
                accS[nt] = __builtin_amdgcn_mfma_f32_16x16x32_bf16(qf[ks], kf, accS[nt], 0, 0, 0);
            }
        }
    }

    float mrow[4] = { NEG_INF, NEG_INF, NEG_INF, NEG_INF };
    #pragma unroll
    for (int nt = 0; nt < 16; nt++)
        #pragma unroll
        for (int r = 0; r < 4; r++) {
            const int col = nt * 16 + i;
            const int row = rb + 4 * g + r;
            float v = accS[nt][r] * SCALE_;
            v = (col <= row) ? v : NEG_INF;
            accS[nt][r] = v;
            mrow[r] = fmaxf(mrow[r], v);
        }
    #pragma unroll
    for (int r = 0; r < 4; r++)
        #pragma unroll
        for (int msk = 1; msk < 16; msk <<= 1)
            mrow[r] = fmaxf(mrow[r], __shfl_xor(mrow[r], msk, 64));

    float lsum[4] = { 0.f, 0.f, 0.f, 0.f };
    #pragma unroll
    for (int nt = 0; nt < 16; nt++)
        #pragma unroll
        for (int r = 0; r < 4; r++) {
            const float p = __expf(accS[nt][r] - mrow[r]);
            accS[nt][r] = p;
            lsum[r] += p;
        }
    #pragma unroll
    for (int r = 0; r < 4; r++)
        #pragma unroll
        for (int msk = 1; msk < 16; msk <<= 1)
            lsum[r] += __shfl_xor(lsum[r], msk, 64);

    f32x4 accO[4];
    #pragma unroll
    for (int ht = 0; ht < 4; ht++) accO[ht] = f32x4{0.f, 0.f, 0.f, 0.f};

    #pragma unroll
    for (int ck = 0; ck < 8; ck++) {
        if (2 * ck <= lim) {
            #pragma unroll
            for (int t2 = 0; t2 < 2; t2++)
                #pragma unroll
                for (int r = 0; r < 4; r++) {
                    const int q = 4 * g + r, kk = t2 * 16 + i;
                    myP[q * 40 + kk] = (short)f2bf(accS[2 * ck + t2][r]);
                }
            asm volatile("s_waitcnt lgkmcnt(0)" ::: "memory");
            const bf16x8 pf = *(const bf16x8*)&myP[i * 40 + g * 8];
            #pragma unroll
            for (int ht = 0; ht < 4; ht++) {
                const bf16x8 vf = *(const bf16x8*)&Vt[(ht * 16 + i) * 264 + ck * 32 + g * 8];
                accO[ht] = __builtin_amdgcn_mfma_f32_16x16x32_bf16(pf, vf, accO[ht], 0, 0, 0);
            }
        }
    }

    float inv[4];
    #pragma unroll
    for (int r = 0; r < 4; r++) inv[r] = 1.f / lsum[r];
    #pragma unroll
    for (int ht = 0; ht < 4; ht++)
        #pragma unroll
        for (int r = 0; r < 4; r++) {
            const int row = rb + 4 * g + r;
            out[((size_t)b * T_ + row) * H_ + ht * 16 + i] = accO[ht][r] * inv[r];
        }
}

extern "C" void kernel_launch(void* const* d_in, const int* in_sizes, int n_in,
                              void* d_out, int out_size, void* d_ws, size_t ws_size,
                              hipStream_t stream) {
    const float* x  = (const float*)d_in[0];
    const float* Wk = (const float*)d_in[1];
    const float* Wq = (const float*)d_in[2];
    const float* Wv = (const float*)d_in[3];
    float* out = (float*)d_out;
    (void)d_ws; (void)ws_size; (void)in_sizes; (void)n_in; (void)out_size;
    att_head_kernel<<<dim3(B_), dim3(1024), 0, stream>>>(x, Wk, Wq, Wv, out);
}